// Round 5
// baseline (686.544 us; speedup 1.0000x reference)
//
#include <hip/hip_runtime.h>
#include <hip/hip_bf16.h>
#include <math.h>

typedef _Float16 f16;
typedef _Float16 f16x8 __attribute__((ext_vector_type(8)));
typedef _Float16 f16x4 __attribute__((ext_vector_type(4)));
typedef _Float16 f16x2 __attribute__((ext_vector_type(2)));
typedef float    f32x4 __attribute__((ext_vector_type(4)));

#define NN 1024      // nodes
#define EE 2048      // edges
#define DD 256       // hidden
#define EDH 128      // edge-MLP hidden
#define TPAD 136     // f16 tile pad (2-way LDS aliasing only)

// ---------------- prep: embed (+bn stats) fused with edge-MLP ----------------

__global__ __launch_bounds__(256) void k_embed_hidden(const float* __restrict__ x,
    const float* __restrict__ lw, const float* __restrict__ lb,
    const float* __restrict__ ea, const float* __restrict__ w1, const float* __restrict__ b1,
    float* __restrict__ y, float* __restrict__ colsum, float* __restrict__ colsq,
    float* __restrict__ hid) {
  int bid = blockIdx.x, t = threadIdx.x;
  if (bid < NN) {
    int n = bid;
    __shared__ float xr[38];
    if (t < 38) xr[t] = x[n*38 + t];
    __syncthreads();
    float s = lb[t];
    const float* w = lw + t*38;
    #pragma unroll
    for (int d = 0; d < 38; d++) s += xr[d] * w[d];
    y[n*DD + t] = s;
    atomicAdd(&colsum[t], s);
    atomicAdd(&colsq[t], s*s);
  } else {
    int e = (bid - NN)*2 + (t >> 7);
    int k = t & 127;
    const float* a = ea + e*4;
    const float* w = w1 + k*4;
    float s = b1[k] + a[0]*w[0] + a[1]*w[1] + a[2]*w[2] + a[3]*w[3];
    hid[e*EDH + k] = 1.f / (1.f + expf(-s));
  }
}

// bn normalize -> xh f32, xc16 f16, Agru h-half f16
__global__ __launch_bounds__(256) void k_bnapply(const float* __restrict__ y,
    const float* __restrict__ colsum, const float* __restrict__ colsq,
    const float* __restrict__ g, const float* __restrict__ b,
    float* __restrict__ xh, f16* __restrict__ xc16, f16* __restrict__ Agru) {
  int i = blockIdx.x*256 + threadIdx.x;
  int c = i & 255, row = i >> 8;
  float mean = colsum[c] * (1.f/1024.f);
  float var  = colsq[c] * (1.f/1024.f) - mean*mean;
  float sc = g[c] / sqrtf(var + 1e-5f);
  float sh = b[c] - mean*sc;
  float v = y[i]*sc + sh;
  xh[i] = v;
  xc16[i] = (f16)v;
  Agru[(size_t)row*512 + 256 + c] = (f16)v;
}

// ---------------- dual CSR build (dst in slots [0,1024), src in [1024,2048)) ----------------

__global__ __launch_bounds__(256) void k_cnt2(const int* __restrict__ ei, int* __restrict__ cntAll) {
  int bid = blockIdx.x, t = threadIdx.x;
  int e = (bid & 7)*256 + t;
  if (bid < 8) atomicAdd(&cntAll[ei[EE + e]], 1);          // dst
  else         atomicAdd(&cntAll[1024 + ei[e]], 1);        // src
}

__global__ __launch_bounds__(1024) void k_scan2(const int* __restrict__ cntAll,
    int* __restrict__ offAll, int* __restrict__ curAll, float* __restrict__ denom) {
  __shared__ int sc[1024];
  int b = blockIdx.x, t = threadIdx.x;
  int base = b*1024;
  int c = cntAll[base + t];
  sc[t] = c; __syncthreads();
  for (int o = 1; o < 1024; o <<= 1) {
    int v = (t >= o) ? sc[t - o] : 0;
    __syncthreads();
    sc[t] += v;
    __syncthreads();
  }
  int ex = sc[t] - c;
  offAll[base + t] = ex; curAll[base + t] = ex;
  if (b == 0) denom[t] = (float)(c > 1 ? c : 1);
}

__global__ __launch_bounds__(256) void k_fill2(const int* __restrict__ ei,
    int* __restrict__ curAll, int* __restrict__ eordS, int* __restrict__ posArr) {
  int bid = blockIdx.x, t = threadIdx.x;
  int e = (bid & 7)*256 + t;
  if (bid < 8) {
    int p = atomicAdd(&curAll[ei[EE + e]], 1);
    posArr[e] = p;
  } else {
    int p = atomicAdd(&curAll[1024 + ei[e]], 1);
    eordS[p] = e;
  }
}

// ---------------- BTb build: BTb[(f*128+k)*256 + d] = nn_w2[(d*256+f)*128 + k] ----------------

__global__ __launch_bounds__(256) void k_w2tr(const float* __restrict__ w2, f16* __restrict__ BTb) {
  __shared__ f16 ls[128][130];
  int f = blockIdx.x, dh = blockIdx.y, t = threadIdx.x;
  int dl = t >> 1, kh = (t & 1) * 64;
  const float* src = w2 + ((size_t)(dh*128 + dl)*256 + f)*128 + kh;
  #pragma unroll
  for (int i = 0; i < 16; i++) {
    f32x4 v = *(const f32x4*)(src + i*4);
    f16x2 a = {(f16)v[0], (f16)v[1]};
    f16x2 b = {(f16)v[2], (f16)v[3]};
    *(f16x2*)(&ls[dl][kh + i*4])     = a;
    *(f16x2*)(&ls[dl][kh + i*4 + 2]) = b;
  }
  __syncthreads();
  int k = t >> 1, dh2 = (t & 1) * 64;
  f16* dst = BTb + ((size_t)f*128 + k)*256 + dh*128 + dh2;
  #pragma unroll
  for (int g = 0; g < 8; g++) {
    f16x8 pk;
    #pragma unroll
    for (int q = 0; q < 8; q++) pk[q] = ls[dh2 + g*8 + q][k];
    *(f16x8*)(dst + g*8) = pk;
  }
}

// Bside[512][256]: rows [0,256) = nn_b2 transposed (Bside[f][d] = nb2[d*256+f]);
// rows [256,512) = root_w copy (Bside[256+f][d] = root_w[f*256+d])
__global__ __launch_bounds__(256) void k_sideB(const float* __restrict__ rw,
    const float* __restrict__ nb2, f16* __restrict__ Bside) {
  int bid = blockIdx.x, t = threadIdx.x;
  if (bid < 64) {                              // root linear: 65536 f32
    int i = bid*256 + t;
    f32x4 v = *(const f32x4*)(rw + (size_t)i*4);
    f16x4 r; r[0]=(f16)v[0]; r[1]=(f16)v[1]; r[2]=(f16)v[2]; r[3]=(f16)v[3];
    *(f16x4*)(Bside + 65536 + (size_t)i*4) = r;
  } else {                                     // b2 transpose, 64x64 tiles
    __shared__ float ls[64][65];
    int fb = bid - 64;
    for (int db = 0; db < 4; db++) {
      int r = t >> 2, cs = (t & 3) * 16;
      const float* s = nb2 + (size_t)(db*64 + r)*256 + fb*64 + cs;
      #pragma unroll
      for (int i = 0; i < 16; i += 4) {
        f32x4 v = *(const f32x4*)(s + i);
        ls[r][cs+i] = v[0]; ls[r][cs+i+1] = v[1]; ls[r][cs+i+2] = v[2]; ls[r][cs+i+3] = v[3];
      }
      __syncthreads();
      int fl = t >> 2, ds2 = (t & 3) * 16;
      f16x8 p0, p1;
      #pragma unroll
      for (int q = 0; q < 8; q++) { p0[q] = (f16)ls[ds2+q][fl]; p1[q] = (f16)ls[ds2+8+q][fl]; }
      f16* d = Bside + (size_t)(fb*64 + fl)*256 + db*64 + ds2;
      *(f16x8*)(d)     = p0;
      *(f16x8*)(d + 8) = p1;
      __syncthreads();
    }
  }
}

__global__ __launch_bounds__(256) void k_castall(const float* __restrict__ s0, f16* __restrict__ d0,
    const float* __restrict__ s1, f16* __restrict__ d1,
    const float* __restrict__ s2, f16* __restrict__ d2,
    const float* __restrict__ s3, f16* __restrict__ d3) {
  int bid = blockIdx.x, t = threadIdx.x;
  const float* src; f16* dst; int i;
  if      (bid < 192)  { src = s0; dst = d0; i = bid*256 + t; }
  else if (bid < 384)  { src = s1; dst = d1; i = (bid-192)*256 + t; }
  else if (bid < 1024) { src = s2; dst = d2; i = (bid-384)*256 + t; }
  else                 { src = s3; dst = d3; i = (bid-1024)*256 + t; }
  f32x4 v = ((const f32x4*)src)[i];
  f16x4 r; r[0]=(f16)v[0]; r[1]=(f16)v[1]; r[2]=(f16)v[2]; r[3]=(f16)v[3];
  ((f16x4*)dst)[i] = r;
}

// ---------------- fused conv GEMM + per-edge contraction ----------------
// Tile [128 rows x 128 k] of T1 for f=p computed in-register (K=256, BK=64),
// dumped to LDS f16 tile, then per out-edge: msg = dot(h[e], tile[src]) + T2[src,p]
// -> msgbuf[pos(e)][p]. No T materialization.

__global__ __launch_bounds__(256) void k_fgemm(const f16* __restrict__ A,
    const f16* __restrict__ BT, const float* __restrict__ hid,
    const int* __restrict__ ei, const int* __restrict__ offAll,
    const int* __restrict__ posArr, const int* __restrict__ eordS,
    const float* __restrict__ T2R, float* __restrict__ msgbuf) {
  __shared__ __align__(16) f16 lds[18432];   // 36.9 KB: staging As[128][72]+Bs[128][72]; tile[128][136]
  f16* As = lds;
  f16* Bs = lds + 128*72;
  // grid swizzle: all 8 m-blocks of panel p on one XCD (p % 8 == raw % 8)
  int raw = blockIdx.x;
  int pmod = raw & 7;
  int q = raw >> 3;
  int m = q & 7;
  int p = (q >> 3)*8 + pmod;
  int m0 = m*128;
  int t = threadIdx.x;
  int lane = t & 63, wv = t >> 6, wm = wv >> 1, wn = wv & 1;
  int lr = lane & 15, lg = lane >> 4;
  int arow = t >> 1, aseg = (t & 1) * 32;
  const f16* Ag = A  + (size_t)(m0 + arow)*256 + aseg;
  const f16* Bg = BT + ((size_t)p*128 + arow)*256 + aseg;
  f32x4 acc[4][4] = {};
  for (int ks = 0; ks < 4; ks++) {
    __syncthreads();
    #pragma unroll
    for (int i = 0; i < 4; i++) {
      *(f16x8*)(&As[arow*72 + aseg + i*8]) = *(const f16x8*)(Ag + ks*64 + i*8);
      *(f16x8*)(&Bs[arow*72 + aseg + i*8]) = *(const f16x8*)(Bg + ks*64 + i*8);
    }
    __syncthreads();
    #pragma unroll
    for (int kk = 0; kk < 2; kk++) {
      f16x8 af[4], bf[4];
      #pragma unroll
      for (int i = 0; i < 4; i++) af[i] = *(const f16x8*)(&As[(wm*64 + i*16 + lr)*72 + kk*32 + lg*8]);
      #pragma unroll
      for (int j = 0; j < 4; j++) bf[j] = *(const f16x8*)(&Bs[(wn*64 + j*16 + lr)*72 + kk*32 + lg*8]);
      #pragma unroll
      for (int i = 0; i < 4; i++)
        #pragma unroll
        for (int j = 0; j < 4; j++)
          acc[i][j] = __builtin_amdgcn_mfma_f32_16x16x32_f16(af[i], bf[j], acc[i][j], 0, 0, 0);
    }
  }
  __syncthreads();
  // dump acc -> f16 tile [128][TPAD]
  #pragma unroll
  for (int i = 0; i < 4; i++)
    #pragma unroll
    for (int j = 0; j < 4; j++)
      #pragma unroll
      for (int v = 0; v < 4; v++) {
        int r = wm*64 + i*16 + lg*4 + v;
        int c = wn*64 + j*16 + lr;
        lds[r*TPAD + c] = (f16)acc[i][j][v];
      }
  __syncthreads();
  // per out-edge contraction (edges of nodes [m0, m0+128) are contiguous in eordS)
  int eS = offAll[1024 + m0];
  int eE = (m0 + 128 < 1024) ? offAll[1024 + m0 + 128] : EE;
  for (int idx = eS + wv; idx < eE; idx += 4) {
    int e = eordS[idx];
    int src = ei[e];
    int r = src - m0;
    float hv0 = hid[e*EDH + lane];
    float hv1 = hid[e*EDH + 64 + lane];
    float t0 = (float)lds[r*TPAD + lane];
    float t1 = (float)lds[r*TPAD + 64 + lane];
    float s = fmaf(hv0, t0, hv1*t1);
    #pragma unroll
    for (int o = 32; o; o >>= 1) s += __shfl_xor(s, o, 64);
    if (lane == 0) msgbuf[(size_t)posArr[e]*256 + p] = s + T2R[(size_t)src*512 + p];
  }
}

// ---------------- fin: segment-sum msgbuf (dst-contiguous), /denom, +root+bias, relu ----------------

__global__ __launch_bounds__(256) void k_fin(const float* __restrict__ msgbuf,
    const int* __restrict__ cntAll, const int* __restrict__ offAll,
    const float* __restrict__ denomB, const float* __restrict__ T2R,
    const float* __restrict__ cb, f16* __restrict__ Agru) {
  int n = blockIdx.x, t = threadIdx.x;
  int deg = cntAll[n], o = offAll[n];
  float s = 0.f;
  for (int j = 0; j < deg; j++) s += msgbuf[(size_t)(o+j)*256 + t];
  float m = s / denomB[n] + T2R[(size_t)n*512 + 256 + t] + cb[t];
  Agru[(size_t)n*512 + t] = (f16)fmaxf(m, 0.f);
}

// ---------------- small GEMM: 64x128 tile. MODE 1: f32 store; MODE 3: bias+relu f16 ----------------

template<int MODE>
__global__ __launch_bounds__(256) void k_gemm_sm(const f16* __restrict__ A,
    const f16* __restrict__ BT, float* __restrict__ C, f16* __restrict__ Ch,
    const float* __restrict__ bias, int K, int lda, int ldb, int N,
    int bsA, int bsB, int bsC, int bsBias) {
  __shared__ __align__(16) f16 As[64*40];
  __shared__ __align__(16) f16 Bs[128*40];
  int t = threadIdx.x;
  int m0 = blockIdx.x*64, n0 = blockIdx.y*128, z = blockIdx.z;
  A  += (size_t)z * bsA;
  BT += (size_t)z * bsB;
  if constexpr (MODE == 1) C += (size_t)z * bsC;
  else { Ch += (size_t)z * bsC; bias += (size_t)z * bsBias; }
  int lane = t & 63, wv = t >> 6, wm = wv >> 1, wn = wv & 1;
  int lr = lane & 15, lk = (lane >> 4) * 8;
  int arow = t >> 2, aseg = (t & 3) * 8;
  f32x4 acc[2][4] = {};
  for (int k0 = 0; k0 < K; k0 += 32) {
    __syncthreads();
    *(f16x8*)(&As[arow*40 + aseg]) = *(const f16x8*)(A + (size_t)(m0 + arow)*lda + k0 + aseg);
    *(f16x8*)(&Bs[arow*40 + aseg]) = *(const f16x8*)(BT + (size_t)(n0 + arow)*ldb + k0 + aseg);
    *(f16x8*)(&Bs[(64+arow)*40 + aseg]) = *(const f16x8*)(BT + (size_t)(n0 + 64 + arow)*ldb + k0 + aseg);
    __syncthreads();
    f16x8 af[2], bf[4];
    #pragma unroll
    for (int i = 0; i < 2; i++) af[i] = *(const f16x8*)(&As[(wm*32 + i*16 + lr)*40 + lk]);
    #pragma unroll
    for (int j = 0; j < 4; j++) bf[j] = *(const f16x8*)(&Bs[(wn*64 + j*16 + lr)*40 + lk]);
    #pragma unroll
    for (int i = 0; i < 2; i++)
      #pragma unroll
      for (int j = 0; j < 4; j++)
        acc[i][j] = __builtin_amdgcn_mfma_f32_16x16x32_f16(af[i], bf[j], acc[i][j], 0, 0, 0);
  }
  #pragma unroll
  for (int i = 0; i < 2; i++)
    #pragma unroll
    for (int j = 0; j < 4; j++)
      #pragma unroll
      for (int v = 0; v < 4; v++) {
        int r = m0 + wm*32 + i*16 + (lane >> 4)*4 + v;
        int cc = n0 + wn*64 + j*16 + lr;
        float val = acc[i][j][v];
        if constexpr (MODE == 1) {
          C[(size_t)r*N + cc] = val;
        } else {
          val += bias[cc];
          val = fmaxf(val, 0.f);
          Ch[(size_t)r*N + cc] = (f16)val;
        }
      }
}

// ---------------- GRU gates ----------------

__global__ __launch_bounds__(256) void k_gate(const float* __restrict__ gi,
    const float* __restrict__ gh, const float* __restrict__ bih, const float* __restrict__ bhh,
    const float* __restrict__ hOld, float* __restrict__ hNew, f16* __restrict__ xc16,
    f16* __restrict__ Agru) {
  int i = blockIdx.x*256 + threadIdx.x;
  int row = i >> 8, c = i & 255;
  const float* gir = gi + (size_t)row*768;
  const float* ghr = gh + (size_t)row*768;
  float ir  = gir[c]     + bih[c],     hr = ghr[c]     + bhh[c];
  float iz  = gir[256+c] + bih[256+c], hz = ghr[256+c] + bhh[256+c];
  float inn = gir[512+c] + bih[512+c], hn = ghr[512+c] + bhh[512+c];
  float r  = 1.f / (1.f + expf(-(ir + hr)));
  float zz = 1.f / (1.f + expf(-(iz + hz)));
  float nn = tanhf(inn + r*hn);
  float hv = (1.f - zz)*nn + zz*hOld[i];
  hNew[i] = hv;
  xc16[i] = (f16)hv;
  Agru[(size_t)row*512 + 256 + c] = (f16)hv;
}

// ---------------- head tail ----------------

__global__ __launch_bounds__(256) void k_mix(const f16* __restrict__ h2,
    const float* __restrict__ w3, const float* __restrict__ b3, float* __restrict__ mix) {
  int b = blockIdx.x, t = threadIdx.x;
  int wv = t >> 6, lane = t & 63;
  int rid = b*4 + wv;
  int m = rid >> 10, row = rid & 1023;
  const f16* hr = h2 + (size_t)(m*1024 + row)*DD;
  const float* w = w3 + m*DD;
  float s = 0.f;
  #pragma unroll
  for (int q = 0; q < 4; q++) { int d = lane + q*64; s += (float)hr[d] * w[d]; }
  #pragma unroll
  for (int o = 32; o; o >>= 1) s += __shfl_down(s, o, 64);
  if (lane == 0) mix[m*1024 + row] = s + b3[m];
}

__global__ __launch_bounds__(256) void k_out(const float* __restrict__ mix, float* __restrict__ out) {
  int i = blockIdx.x*256 + threadIdx.x;
  float v[10]; float mu = 0.f;
  #pragma unroll
  for (int m = 0; m < 10; m++) { v[m] = mix[m*1024 + i]; mu += v[m]; }
  mu *= 0.1f;
  float var = 0.f;
  #pragma unroll
  for (int m = 0; m < 10; m++) { float d = v[m] - mu; var += d*d; }
  var *= (1.f/9.f);
  out[i] = mu;
  out[1024 + i] = sqrtf(var + 1e-5f);
}

// ---------------- launch ----------------

extern "C" void kernel_launch(void* const* d_in, const int* in_sizes, int n_in,
                              void* d_out, int out_size, void* d_ws, size_t ws_size,
                              hipStream_t stream) {
  const float* x         = (const float*)d_in[0];
  const float* edge_attr = (const float*)d_in[1];
  const int*   edge_idx  = (const int*)  d_in[2];
  const float* lin_w     = (const float*)d_in[3];
  const float* lin_b     = (const float*)d_in[4];
  const float* bn_g      = (const float*)d_in[5];
  const float* bn_b      = (const float*)d_in[6];
  const float* nn_w1     = (const float*)d_in[7];
  const float* nn_b1     = (const float*)d_in[8];
  const float* nn_w2     = (const float*)d_in[9];
  const float* nn_b2     = (const float*)d_in[10];
  const float* root_w    = (const float*)d_in[11];
  const float* conv_b    = (const float*)d_in[12];
  const float* gru_wih   = (const float*)d_in[13];
  const float* gru_whh   = (const float*)d_in[14];
  const float* gru_bih   = (const float*)d_in[15];
  const float* gru_bhh   = (const float*)d_in[16];
  const float* mlp_w1    = (const float*)d_in[17];
  const float* mlp_b1    = (const float*)d_in[18];
  const float* mlp_w2    = (const float*)d_in[19];
  const float* mlp_b2    = (const float*)d_in[20];
  const float* mlp_w3    = (const float*)d_in[21];
  const float* mlp_b3    = (const float*)d_in[22];
  float* out = (float*)d_out;

  char* w = (char*)d_ws;
  size_t o = 0;
  auto nxt = [&](size_t b) -> size_t { size_t r = o; o += (b + 255) & ~(size_t)255; return r; };
  float* y      = (float*)(w + nxt(1048576));
  float* colsum = (float*)(w + nxt(1024));
  float* colsq  = (float*)(w + nxt(1024));
  float* xh     = (float*)(w + nxt(1048576));
  float* h      = (float*)(w + nxt(1048576));
  f16*   xc16   = (f16*)  (w + nxt(524288));
  float* hid    = (float*)(w + nxt(1048576));
  int*   cntAll = (int*)  (w + nxt(8192));
  int*   offAll = (int*)  (w + nxt(8192));
  int*   curAll = (int*)  (w + nxt(8192));
  float* denomB = (float*)(w + nxt(4096));
  int*   eordS  = (int*)  (w + nxt(8192));
  int*   posArr = (int*)  (w + nxt(8192));
  f16*   BTb    = (f16*)  (w + nxt((size_t)32768*256*2));       // 16.8 MB
  f16*   Bside  = (f16*)  (w + nxt((size_t)512*256*2));         // 256 KB
  float* T2R    = (float*)(w + nxt((size_t)1024*512*4));        // 2 MB
  float* msgbuf = (float*)(w + nxt((size_t)EE*256*4));          // 2 MB
  f16*   Agru   = (f16*)  (w + nxt(1048576));                   // [1024][512] = [m | h]
  float* G      = (float*)(w + nxt((size_t)2*1024*768*4));      // gi, gh
  f16*   Wb     = (f16*)  (w + nxt(786432));                    // [2][768][256]
  f16*   w1T    = (f16*)  (w + nxt(1310720));
  f16*   w2T    = (f16*)  (w + nxt(1310720));
  f16*   h1     = (f16*)  (w + nxt(5242880));
  f16*   h2     = (f16*)  (w + nxt(5242880));
  float* mixb   = (float*)(w + nxt(40960));
  if (o > ws_size) return;

  hipMemsetAsync(colsum, 0, 2048, stream);   // colsum + colsq contiguous
  hipMemsetAsync(cntAll, 0, 8192, stream);

  k_embed_hidden<<<2048, 256, 0, stream>>>(x, lin_w, lin_b, edge_attr, nn_w1, nn_b1,
                                           y, colsum, colsq, hid);
  k_bnapply<<<1024, 256, 0, stream>>>(y, colsum, colsq, bn_g, bn_b, xh, xc16, Agru);
  k_cnt2 <<<16, 256, 0, stream>>>(edge_idx, cntAll);
  k_scan2<<<2, 1024, 0, stream>>>(cntAll, offAll, curAll, denomB);
  k_fill2<<<16, 256, 0, stream>>>(edge_idx, curAll, eordS, posArr);
  k_w2tr <<<dim3(256, 2), 256, 0, stream>>>(nn_w2, BTb);
  k_sideB<<<68, 256, 0, stream>>>(root_w, nn_b2, Bside);
  k_castall<<<1664, 256, 0, stream>>>(gru_wih, Wb, gru_whh, Wb + 196608,
                                      mlp_w1, w1T, mlp_w2, w2T);

  for (int it = 0; it < 3; it++) {
    const float* hOld = (it == 0) ? xh : h;
    // side terms first (fgemm epilogue reads T2R)
    k_gemm_sm<1><<<dim3(16, 4, 1), 256, 0, stream>>>(xc16, Bside, T2R,
        nullptr, nullptr, 256, 256, 256, 512, 0, 0, 0, 0);
    k_fgemm<<<2048, 256, 0, stream>>>(xc16, BTb, hid, edge_idx, offAll,
                                      posArr, eordS, T2R, msgbuf);
    k_fin  <<<1024, 256, 0, stream>>>(msgbuf, cntAll, offAll, denomB, T2R, conv_b, Agru);
    k_gemm_sm<1><<<dim3(16, 6, 2), 256, 0, stream>>>(Agru, Wb, G,
        nullptr, nullptr, 256, 512, 256, 768, 256, 196608, 786432, 0);
    k_gate<<<1024, 256, 0, stream>>>(G, G + 786432, gru_bih, gru_bhh, hOld, h, xc16, Agru);
  }

  k_gemm_sm<3><<<dim3(16, 2, 10), 256, 0, stream>>>(Agru + 256, w1T, nullptr, h1, mlp_b1,
      256, 512, 256, 256, 0, 65536, 262144, 256);
  k_gemm_sm<3><<<dim3(16, 2, 10), 256, 0, stream>>>(h1, w2T, nullptr, h2, mlp_b2,
      256, 256, 256, 256, 262144, 65536, 262144, 256);
  k_mix<<<2560, 256, 0, stream>>>(h2, mlp_w3, mlp_b3, mixb);
  k_out<<<4, 256, 0, stream>>>(mixb, out);
}

// Round 6
// 333.929 us; speedup vs baseline: 2.0560x; 2.0560x over previous
//
#include <hip/hip_runtime.h>
#include <hip/hip_bf16.h>
#include <math.h>

typedef _Float16 f16;
typedef _Float16 f16x8 __attribute__((ext_vector_type(8)));
typedef _Float16 f16x4 __attribute__((ext_vector_type(4)));
typedef _Float16 f16x2 __attribute__((ext_vector_type(2)));
typedef float    f32x4 __attribute__((ext_vector_type(4)));

#define NN 1024      // nodes
#define EE 2048      // edges
#define DD 256       // hidden
#define EDH 128      // edge-MLP hidden
#define TPAD 136     // f16 tile pad (16B-aligned rows)

// ---------------- prep: embed (+bn stats) fused with edge-MLP (hid -> f16) ----------------

__global__ __launch_bounds__(256) void k_embed_hidden(const float* __restrict__ x,
    const float* __restrict__ lw, const float* __restrict__ lb,
    const float* __restrict__ ea, const float* __restrict__ w1, const float* __restrict__ b1,
    float* __restrict__ y, float* __restrict__ colsum, float* __restrict__ colsq,
    f16* __restrict__ h16e) {
  int bid = blockIdx.x, t = threadIdx.x;
  if (bid < NN) {
    int n = bid;
    __shared__ float xr[38];
    if (t < 38) xr[t] = x[n*38 + t];
    __syncthreads();
    float s = lb[t];
    const float* w = lw + t*38;
    #pragma unroll
    for (int d = 0; d < 38; d++) s += xr[d] * w[d];
    y[n*DD + t] = s;
    atomicAdd(&colsum[t], s);
    atomicAdd(&colsq[t], s*s);
  } else {
    int e = (bid - NN)*2 + (t >> 7);
    int k = t & 127;
    const float* a = ea + e*4;
    const float* w = w1 + k*4;
    float s = b1[k] + a[0]*w[0] + a[1]*w[1] + a[2]*w[2] + a[3]*w[3];
    h16e[e*EDH + k] = (f16)(1.f / (1.f + expf(-s)));
  }
}

// bn normalize -> xh f32, xc16 f16, Agru h-half f16
__global__ __launch_bounds__(256) void k_bnapply(const float* __restrict__ y,
    const float* __restrict__ colsum, const float* __restrict__ colsq,
    const float* __restrict__ g, const float* __restrict__ b,
    float* __restrict__ xh, f16* __restrict__ xc16, f16* __restrict__ Agru) {
  int i = blockIdx.x*256 + threadIdx.x;
  int c = i & 255, row = i >> 8;
  float mean = colsum[c] * (1.f/1024.f);
  float var  = colsq[c] * (1.f/1024.f) - mean*mean;
  float sc = g[c] / sqrtf(var + 1e-5f);
  float sh = b[c] - mean*sc;
  float v = y[i]*sc + sh;
  xh[i] = v;
  xc16[i] = (f16)v;
  Agru[(size_t)row*512 + 256 + c] = (f16)v;
}

// ---------------- dual CSR build (dst in slots [0,1024), src in [1024,2048)) ----------------

__global__ __launch_bounds__(256) void k_cnt2(const int* __restrict__ ei, int* __restrict__ cntAll) {
  int bid = blockIdx.x, t = threadIdx.x;
  int e = (bid & 7)*256 + t;
  if (bid < 8) atomicAdd(&cntAll[ei[EE + e]], 1);          // dst
  else         atomicAdd(&cntAll[1024 + ei[e]], 1);        // src
}

__global__ __launch_bounds__(1024) void k_scan2(const int* __restrict__ cntAll,
    int* __restrict__ offAll, int* __restrict__ curAll, float* __restrict__ denom) {
  __shared__ int sc[1024];
  int b = blockIdx.x, t = threadIdx.x;
  int base = b*1024;
  int c = cntAll[base + t];
  sc[t] = c; __syncthreads();
  for (int o = 1; o < 1024; o <<= 1) {
    int v = (t >= o) ? sc[t - o] : 0;
    __syncthreads();
    sc[t] += v;
    __syncthreads();
  }
  int ex = sc[t] - c;
  offAll[base + t] = ex; curAll[base + t] = ex;
  if (b == 0) denom[t] = (float)(c > 1 ? c : 1);
}

__global__ __launch_bounds__(256) void k_fill2(const int* __restrict__ ei,
    int* __restrict__ curAll, int* __restrict__ eordS, int* __restrict__ posArr) {
  int bid = blockIdx.x, t = threadIdx.x;
  int e = (bid & 7)*256 + t;
  if (bid < 8) {
    int p = atomicAdd(&curAll[ei[EE + e]], 1);
    posArr[e] = p;
  } else {
    int p = atomicAdd(&curAll[1024 + ei[e]], 1);
    eordS[p] = e;
  }
}

// packed edge record in src-order: e | src<<11 | pos<<21
__global__ __launch_bounds__(256) void k_edgerec(const int* __restrict__ eordS,
    const int* __restrict__ ei, const int* __restrict__ posArr, unsigned* __restrict__ rec) {
  int idx = blockIdx.x*256 + threadIdx.x;
  int e = eordS[idx];
  rec[idx] = (unsigned)e | ((unsigned)ei[e] << 11) | ((unsigned)posArr[e] << 21);
}

// ---------------- BTb build: BTb[(f*128+k)*256 + d] = nn_w2[(d*256+f)*128 + k] ----------------

__global__ __launch_bounds__(256) void k_w2tr(const float* __restrict__ w2, f16* __restrict__ BTb) {
  __shared__ f16 ls[128][130];
  int f = blockIdx.x, dh = blockIdx.y, t = threadIdx.x;
  int dl = t >> 1, kh = (t & 1) * 64;
  const float* src = w2 + ((size_t)(dh*128 + dl)*256 + f)*128 + kh;
  #pragma unroll
  for (int i = 0; i < 16; i++) {
    f32x4 v = *(const f32x4*)(src + i*4);
    f16x2 a = {(f16)v[0], (f16)v[1]};
    f16x2 b = {(f16)v[2], (f16)v[3]};
    *(f16x2*)(&ls[dl][kh + i*4])     = a;
    *(f16x2*)(&ls[dl][kh + i*4 + 2]) = b;
  }
  __syncthreads();
  int k = t >> 1, dh2 = (t & 1) * 64;
  f16* dst = BTb + ((size_t)f*128 + k)*256 + dh*128 + dh2;
  #pragma unroll
  for (int g = 0; g < 8; g++) {
    f16x8 pk;
    #pragma unroll
    for (int q = 0; q < 8; q++) pk[q] = ls[dh2 + g*8 + q][k];
    *(f16x8*)(dst + g*8) = pk;
  }
}

// Bside[512][256]: rows [0,256) = nn_b2^T; rows [256,512) = root_w
__global__ __launch_bounds__(256) void k_sideB(const float* __restrict__ rw,
    const float* __restrict__ nb2, f16* __restrict__ Bside) {
  int bid = blockIdx.x, t = threadIdx.x;
  if (bid < 64) {
    int i = bid*256 + t;
    f32x4 v = *(const f32x4*)(rw + (size_t)i*4);
    f16x4 r; r[0]=(f16)v[0]; r[1]=(f16)v[1]; r[2]=(f16)v[2]; r[3]=(f16)v[3];
    *(f16x4*)(Bside + 65536 + (size_t)i*4) = r;
  } else {
    __shared__ float ls[64][65];
    int fb = bid - 64;
    for (int db = 0; db < 4; db++) {
      int r = t >> 2, cs = (t & 3) * 16;
      const float* s = nb2 + (size_t)(db*64 + r)*256 + fb*64 + cs;
      #pragma unroll
      for (int i = 0; i < 16; i += 4) {
        f32x4 v = *(const f32x4*)(s + i);
        ls[r][cs+i] = v[0]; ls[r][cs+i+1] = v[1]; ls[r][cs+i+2] = v[2]; ls[r][cs+i+3] = v[3];
      }
      __syncthreads();
      int fl = t >> 2, ds2 = (t & 3) * 16;
      f16x8 p0, p1;
      #pragma unroll
      for (int q = 0; q < 8; q++) { p0[q] = (f16)ls[ds2+q][fl]; p1[q] = (f16)ls[ds2+8+q][fl]; }
      f16* d = Bside + (size_t)(fb*64 + fl)*256 + db*64 + ds2;
      *(f16x8*)(d)     = p0;
      *(f16x8*)(d + 8) = p1;
      __syncthreads();
    }
  }
}

__global__ __launch_bounds__(256) void k_castall(const float* __restrict__ s0, f16* __restrict__ d0,
    const float* __restrict__ s1, f16* __restrict__ d1,
    const float* __restrict__ s2, f16* __restrict__ d2,
    const float* __restrict__ s3, f16* __restrict__ d3) {
  int bid = blockIdx.x, t = threadIdx.x;
  const float* src; f16* dst; int i;
  if      (bid < 192)  { src = s0; dst = d0; i = bid*256 + t; }
  else if (bid < 384)  { src = s1; dst = d1; i = (bid-192)*256 + t; }
  else if (bid < 1024) { src = s2; dst = d2; i = (bid-384)*256 + t; }
  else                 { src = s3; dst = d3; i = (bid-1024)*256 + t; }
  f32x4 v = ((const f32x4*)src)[i];
  f16x4 r; r[0]=(f16)v[0]; r[1]=(f16)v[1]; r[2]=(f16)v[2]; r[3]=(f16)v[3];
  ((f16x4*)dst)[i] = r;
}

// ---------------- fused conv GEMM + thread-per-edge contraction ----------------
// Tile [128 src rows x 128 k] of T for f=p computed in-register (K=256, BK=64),
// dumped to LDS f16 tile; then ONE THREAD PER EDGE does a 128-dot of h16[e]
// against tile[src] and writes msgbuf[pos(e)][p] (+ b2 side term).

__global__ __launch_bounds__(256) void k_fgemm(const f16* __restrict__ A,
    const f16* __restrict__ BT, const f16* __restrict__ h16e,
    const int* __restrict__ offAll, const unsigned* __restrict__ rec,
    const float* __restrict__ T2R, float* __restrict__ msgbuf) {
  __shared__ __align__(16) f16 lds[18432];   // staging As[128][72]+Bs[128][72] / tile[128][136]
  f16* As = lds;
  f16* Bs = lds + 128*72;
  // grid swizzle: all 8 m-blocks of panel p on one XCD (p % 8 == raw % 8)
  int raw = blockIdx.x;
  int pmod = raw & 7;
  int q = raw >> 3;
  int m = q & 7;
  int p = (q >> 3)*8 + pmod;
  int m0 = m*128;
  int t = threadIdx.x;
  int lane = t & 63, wv = t >> 6, wm = wv >> 1, wn = wv & 1;
  int lr = lane & 15, lg = lane >> 4;
  int arow = t >> 1, aseg = (t & 1) * 32;
  const f16* Ag = A  + (size_t)(m0 + arow)*256 + aseg;
  const f16* Bg = BT + ((size_t)p*128 + arow)*256 + aseg;
  f32x4 acc[4][4] = {};
  for (int ks = 0; ks < 4; ks++) {
    __syncthreads();
    #pragma unroll
    for (int i = 0; i < 4; i++) {
      *(f16x8*)(&As[arow*72 + aseg + i*8]) = *(const f16x8*)(Ag + ks*64 + i*8);
      *(f16x8*)(&Bs[arow*72 + aseg + i*8]) = *(const f16x8*)(Bg + ks*64 + i*8);
    }
    __syncthreads();
    #pragma unroll
    for (int kk = 0; kk < 2; kk++) {
      f16x8 af[4], bf[4];
      #pragma unroll
      for (int i = 0; i < 4; i++) af[i] = *(const f16x8*)(&As[(wm*64 + i*16 + lr)*72 + kk*32 + lg*8]);
      #pragma unroll
      for (int j = 0; j < 4; j++) bf[j] = *(const f16x8*)(&Bs[(wn*64 + j*16 + lr)*72 + kk*32 + lg*8]);
      #pragma unroll
      for (int i = 0; i < 4; i++)
        #pragma unroll
        for (int j = 0; j < 4; j++)
          acc[i][j] = __builtin_amdgcn_mfma_f32_16x16x32_f16(af[i], bf[j], acc[i][j], 0, 0, 0);
    }
  }
  __syncthreads();
  // dump acc -> f16 tile [128][TPAD]
  #pragma unroll
  for (int i = 0; i < 4; i++)
    #pragma unroll
    for (int j = 0; j < 4; j++)
      #pragma unroll
      for (int v = 0; v < 4; v++) {
        int r = wm*64 + i*16 + lg*4 + v;
        int c = wn*64 + j*16 + lr;
        lds[r*TPAD + c] = (f16)acc[i][j][v];
      }
  __syncthreads();
  // thread-per-edge contraction (edges of nodes [m0, m0+128) contiguous in rec)
  int eS = offAll[1024 + m0];
  int eE = (m0 + 128 < 1024) ? offAll[1024 + m0 + 128] : EE;
  for (int idx = eS + t; idx < eE; idx += 256) {
    unsigned u = rec[idx];
    int e   = u & 2047;
    int src = (u >> 11) & 1023;
    int pos = u >> 21;
    int r = src - m0;
    const f16* hp = h16e + (size_t)e*EDH;
    float s = 0.f;
    #pragma unroll
    for (int i = 0; i < 16; i++) {
      f16x8 hv = *(const f16x8*)(hp + i*8);
      f16x8 tv = *(const f16x8*)(&lds[r*TPAD + i*8]);
      #pragma unroll
      for (int qq = 0; qq < 8; qq++) s += (float)hv[qq] * (float)tv[qq];
    }
    msgbuf[(size_t)pos*256 + p] = s + T2R[(size_t)src*512 + p];
  }
}

// ---------------- fin: segment-sum msgbuf (dst-contiguous), /denom, +root+bias, relu ----------------

__global__ __launch_bounds__(256) void k_fin(const float* __restrict__ msgbuf,
    const int* __restrict__ cntAll, const int* __restrict__ offAll,
    const float* __restrict__ denomB, const float* __restrict__ T2R,
    const float* __restrict__ cb, f16* __restrict__ Agru) {
  int n = blockIdx.x, t = threadIdx.x;
  int deg = cntAll[n], o = offAll[n];
  float s = 0.f;
  for (int j = 0; j < deg; j++) s += msgbuf[(size_t)(o+j)*256 + t];
  float m = s / denomB[n] + T2R[(size_t)n*512 + 256 + t] + cb[t];
  Agru[(size_t)n*512 + t] = (f16)fmaxf(m, 0.f);
}

// ---------------- small GEMM: 64x128 tile. MODE 1: f32 store; MODE 3: bias+relu f16 ----------------

template<int MODE>
__global__ __launch_bounds__(256) void k_gemm_sm(const f16* __restrict__ A,
    const f16* __restrict__ BT, float* __restrict__ C, f16* __restrict__ Ch,
    const float* __restrict__ bias, int K, int lda, int ldb, int N,
    int bsA, int bsB, int bsC, int bsBias) {
  __shared__ __align__(16) f16 As[64*40];
  __shared__ __align__(16) f16 Bs[128*40];
  int t = threadIdx.x;
  int m0 = blockIdx.x*64, n0 = blockIdx.y*128, z = blockIdx.z;
  A  += (size_t)z * bsA;
  BT += (size_t)z * bsB;
  if constexpr (MODE == 1) C += (size_t)z * bsC;
  else { Ch += (size_t)z * bsC; bias += (size_t)z * bsBias; }
  int lane = t & 63, wv = t >> 6, wm = wv >> 1, wn = wv & 1;
  int lr = lane & 15, lk = (lane >> 4) * 8;
  int arow = t >> 2, aseg = (t & 3) * 8;
  f32x4 acc[2][4] = {};
  for (int k0 = 0; k0 < K; k0 += 32) {
    __syncthreads();
    *(f16x8*)(&As[arow*40 + aseg]) = *(const f16x8*)(A + (size_t)(m0 + arow)*lda + k0 + aseg);
    *(f16x8*)(&Bs[arow*40 + aseg]) = *(const f16x8*)(BT + (size_t)(n0 + arow)*ldb + k0 + aseg);
    *(f16x8*)(&Bs[(64+arow)*40 + aseg]) = *(const f16x8*)(BT + (size_t)(n0 + 64 + arow)*ldb + k0 + aseg);
    __syncthreads();
    f16x8 af[2], bf[4];
    #pragma unroll
    for (int i = 0; i < 2; i++) af[i] = *(const f16x8*)(&As[(wm*32 + i*16 + lr)*40 + lk]);
    #pragma unroll
    for (int j = 0; j < 4; j++) bf[j] = *(const f16x8*)(&Bs[(wn*64 + j*16 + lr)*40 + lk]);
    #pragma unroll
    for (int i = 0; i < 2; i++)
      #pragma unroll
      for (int j = 0; j < 4; j++)
        acc[i][j] = __builtin_amdgcn_mfma_f32_16x16x32_f16(af[i], bf[j], acc[i][j], 0, 0, 0);
  }
  #pragma unroll
  for (int i = 0; i < 2; i++)
    #pragma unroll
    for (int j = 0; j < 4; j++)
      #pragma unroll
      for (int v = 0; v < 4; v++) {
        int r = m0 + wm*32 + i*16 + (lane >> 4)*4 + v;
        int cc = n0 + wn*64 + j*16 + lr;
        float val = acc[i][j][v];
        if constexpr (MODE == 1) {
          C[(size_t)r*N + cc] = val;
        } else {
          val += bias[cc];
          val = fmaxf(val, 0.f);
          Ch[(size_t)r*N + cc] = (f16)val;
        }
      }
}

// ---------------- GRU gates ----------------

__global__ __launch_bounds__(256) void k_gate(const float* __restrict__ gi,
    const float* __restrict__ gh, const float* __restrict__ bih, const float* __restrict__ bhh,
    const float* __restrict__ hOld, float* __restrict__ hNew, f16* __restrict__ xc16,
    f16* __restrict__ Agru) {
  int i = blockIdx.x*256 + threadIdx.x;
  int row = i >> 8, c = i & 255;
  const float* gir = gi + (size_t)row*768;
  const float* ghr = gh + (size_t)row*768;
  float ir  = gir[c]     + bih[c],     hr = ghr[c]     + bhh[c];
  float iz  = gir[256+c] + bih[256+c], hz = ghr[256+c] + bhh[256+c];
  float inn = gir[512+c] + bih[512+c], hn = ghr[512+c] + bhh[512+c];
  float r  = 1.f / (1.f + expf(-(ir + hr)));
  float zz = 1.f / (1.f + expf(-(iz + hz)));
  float nn = tanhf(inn + r*hn);
  float hv = (1.f - zz)*nn + zz*hOld[i];
  hNew[i] = hv;
  xc16[i] = (f16)hv;
  Agru[(size_t)row*512 + 256 + c] = (f16)hv;
}

// ---------------- head tail ----------------

__global__ __launch_bounds__(256) void k_mix(const f16* __restrict__ h2,
    const float* __restrict__ w3, const float* __restrict__ b3, float* __restrict__ mix) {
  int b = blockIdx.x, t = threadIdx.x;
  int wv = t >> 6, lane = t & 63;
  int rid = b*4 + wv;
  int m = rid >> 10, row = rid & 1023;
  const f16* hr = h2 + (size_t)(m*1024 + row)*DD;
  const float* w = w3 + m*DD;
  float s = 0.f;
  #pragma unroll
  for (int q = 0; q < 4; q++) { int d = lane + q*64; s += (float)hr[d] * w[d]; }
  #pragma unroll
  for (int o = 32; o; o >>= 1) s += __shfl_down(s, o, 64);
  if (lane == 0) mix[m*1024 + row] = s + b3[m];
}

__global__ __launch_bounds__(256) void k_out(const float* __restrict__ mix, float* __restrict__ out) {
  int i = blockIdx.x*256 + threadIdx.x;
  float v[10]; float mu = 0.f;
  #pragma unroll
  for (int m = 0; m < 10; m++) { v[m] = mix[m*1024 + i]; mu += v[m]; }
  mu *= 0.1f;
  float var = 0.f;
  #pragma unroll
  for (int m = 0; m < 10; m++) { float d = v[m] - mu; var += d*d; }
  var *= (1.f/9.f);
  out[i] = mu;
  out[1024 + i] = sqrtf(var + 1e-5f);
}

// ---------------- launch ----------------

extern "C" void kernel_launch(void* const* d_in, const int* in_sizes, int n_in,
                              void* d_out, int out_size, void* d_ws, size_t ws_size,
                              hipStream_t stream) {
  const float* x         = (const float*)d_in[0];
  const float* edge_attr = (const float*)d_in[1];
  const int*   edge_idx  = (const int*)  d_in[2];
  const float* lin_w     = (const float*)d_in[3];
  const float* lin_b     = (const float*)d_in[4];
  const float* bn_g      = (const float*)d_in[5];
  const float* bn_b      = (const float*)d_in[6];
  const float* nn_w1     = (const float*)d_in[7];
  const float* nn_b1     = (const float*)d_in[8];
  const float* nn_w2     = (const float*)d_in[9];
  const float* nn_b2     = (const float*)d_in[10];
  const float* root_w    = (const float*)d_in[11];
  const float* conv_b    = (const float*)d_in[12];
  const float* gru_wih   = (const float*)d_in[13];
  const float* gru_whh   = (const float*)d_in[14];
  const float* gru_bih   = (const float*)d_in[15];
  const float* gru_bhh   = (const float*)d_in[16];
  const float* mlp_w1    = (const float*)d_in[17];
  const float* mlp_b1    = (const float*)d_in[18];
  const float* mlp_w2    = (const float*)d_in[19];
  const float* mlp_b2    = (const float*)d_in[20];
  const float* mlp_w3    = (const float*)d_in[21];
  const float* mlp_b3    = (const float*)d_in[22];
  float* out = (float*)d_out;

  char* w = (char*)d_ws;
  size_t o = 0;
  auto nxt = [&](size_t b) -> size_t { size_t r = o; o += (b + 255) & ~(size_t)255; return r; };
  float* y      = (float*)(w + nxt(1048576));
  float* colsum = (float*)(w + nxt(1024));
  float* colsq  = (float*)(w + nxt(1024));
  float* xh     = (float*)(w + nxt(1048576));
  float* h      = (float*)(w + nxt(1048576));
  f16*   xc16   = (f16*)  (w + nxt(524288));
  f16*   h16e   = (f16*)  (w + nxt(524288));                    // [2048][128] f16
  int*   cntAll = (int*)  (w + nxt(8192));
  int*   offAll = (int*)  (w + nxt(8192));
  int*   curAll = (int*)  (w + nxt(8192));
  float* denomB = (float*)(w + nxt(4096));
  int*   eordS  = (int*)  (w + nxt(8192));
  int*   posArr = (int*)  (w + nxt(8192));
  unsigned* rec = (unsigned*)(w + nxt(8192));
  f16*   BTb    = (f16*)  (w + nxt((size_t)32768*256*2));       // 16.8 MB
  f16*   Bside  = (f16*)  (w + nxt((size_t)512*256*2));         // 256 KB
  float* T2R    = (float*)(w + nxt((size_t)1024*512*4));        // 2 MB
  float* msgbuf = (float*)(w + nxt((size_t)EE*256*4));          // 2 MB
  f16*   Agru   = (f16*)  (w + nxt(1048576));                   // [1024][512] = [m | h]
  float* G      = (float*)(w + nxt((size_t)2*1024*768*4));      // gi, gh
  f16*   Wb     = (f16*)  (w + nxt(786432));                    // [2][768][256]
  f16*   w1T    = (f16*)  (w + nxt(1310720));
  f16*   w2T    = (f16*)  (w + nxt(1310720));
  f16*   h1     = (f16*)  (w + nxt(5242880));
  f16*   h2     = (f16*)  (w + nxt(5242880));
  float* mixb   = (float*)(w + nxt(40960));
  if (o > ws_size) return;

  hipMemsetAsync(colsum, 0, 2048, stream);   // colsum + colsq contiguous
  hipMemsetAsync(cntAll, 0, 8192, stream);

  k_embed_hidden<<<2048, 256, 0, stream>>>(x, lin_w, lin_b, edge_attr, nn_w1, nn_b1,
                                           y, colsum, colsq, h16e);
  k_bnapply<<<1024, 256, 0, stream>>>(y, colsum, colsq, bn_g, bn_b, xh, xc16, Agru);
  k_cnt2  <<<16, 256, 0, stream>>>(edge_idx, cntAll);
  k_scan2 <<<2, 1024, 0, stream>>>(cntAll, offAll, curAll, denomB);
  k_fill2 <<<16, 256, 0, stream>>>(edge_idx, curAll, eordS, posArr);
  k_edgerec<<<8, 256, 0, stream>>>(eordS, edge_idx, posArr, rec);
  k_w2tr  <<<dim3(256, 2), 256, 0, stream>>>(nn_w2, BTb);
  k_sideB <<<68, 256, 0, stream>>>(root_w, nn_b2, Bside);
  k_castall<<<1664, 256, 0, stream>>>(gru_wih, Wb, gru_whh, Wb + 196608,
                                      mlp_w1, w1T, mlp_w2, w2T);

  for (int it = 0; it < 3; it++) {
    const float* hOld = (it == 0) ? xh : h;
    k_gemm_sm<1><<<dim3(16, 4, 1), 256, 0, stream>>>(xc16, Bside, T2R,
        nullptr, nullptr, 256, 256, 256, 512, 0, 0, 0, 0);
    k_fgemm<<<2048, 256, 0, stream>>>(xc16, BTb, h16e, offAll, rec, T2R, msgbuf);
    k_fin  <<<1024, 256, 0, stream>>>(msgbuf, cntAll, offAll, denomB, T2R, conv_b, Agru);
    k_gemm_sm<1><<<dim3(16, 6, 2), 256, 0, stream>>>(Agru, Wb, G,
        nullptr, nullptr, 256, 512, 256, 768, 256, 196608, 786432, 0);
    k_gate<<<1024, 256, 0, stream>>>(G, G + 786432, gru_bih, gru_bhh, hOld, h, xc16, Agru);
  }

  k_gemm_sm<3><<<dim3(16, 2, 10), 256, 0, stream>>>(Agru + 256, w1T, nullptr, h1, mlp_b1,
      256, 512, 256, 256, 0, 65536, 262144, 256);
  k_gemm_sm<3><<<dim3(16, 2, 10), 256, 0, stream>>>(h1, w2T, nullptr, h2, mlp_b2,
      256, 256, 256, 256, 262144, 65536, 262144, 256);
  k_mix<<<2560, 256, 0, stream>>>(h2, mlp_w3, mlp_b3, mixb);
  k_out<<<4, 256, 0, stream>>>(mixb, out);
}